// Round 1
// baseline (2004.952 us; speedup 1.0000x reference)
//
#include <hip/hip_runtime.h>

#define Dm 96
#define ICn 16
#define OCn 16
#define HYPn 128
#define BSn 4
#define KVOL 27
#define KWN (OCn*ICn*KVOL)   // 6912 weights per sample

// ---------------- hypernetwork: per-sample conv weights ----------------
__global__ __launch_bounds__(256)
void hyper_gemm_kernel(const float* __restrict__ hyp, const float* __restrict__ Wk,
                       const float* __restrict__ bk, float* __restrict__ kw)
{
    int t = blockIdx.x * 256 + threadIdx.x;
    if (t >= BSn * KWN) return;
    int b = t / KWN;
    int r = t - b * KWN;
    const float4* w = (const float4*)(Wk + (long)r * HYPn);
    const float4* h = (const float4*)(hyp + (long)b * HYPn);
    float acc = bk[r];
#pragma unroll
    for (int k = 0; k < HYPn/4; ++k) {
        float4 a = h[k], c = w[k];
        acc += a.x*c.x + a.y*c.y + a.z*c.z + a.w*c.w;
    }
    kw[t] = acc;   // layout [b][oc][ic][kz][ky][kx] flat per sample
}

__global__ __launch_bounds__(64)
void hyper_bias_kernel(const float* __restrict__ hyp, const float* __restrict__ Wb,
                       const float* __restrict__ bb, float* __restrict__ bias)
{
    int t = threadIdx.x;          // 64 = 4 samples * 16 oc
    int b = t >> 4, oc = t & 15;
    const float4* w = (const float4*)(Wb + (long)oc * HYPn);
    const float4* h = (const float4*)(hyp + (long)b * HYPn);
    float acc = bb[oc];
#pragma unroll
    for (int k = 0; k < HYPn/4; ++k) {
        float4 a = h[k], c = w[k];
        acc += a.x*c.x + a.y*c.y + a.z*c.z + a.w*c.w;
    }
    bias[t] = acc;                // [b][oc]
}

// ---------------- per-sample 3D conv ----------------
#define TX 32
#define TY 4
#define TZ 4
#define ICCH 4   // input channels staged per chunk

__global__ __launch_bounds__(256)
void conv_kernel(const float* __restrict__ x, const float* __restrict__ kw,
                 const float* __restrict__ bias, float* __restrict__ out)
{
    __shared__ float wlds[KWN];                          // 27648 B: all weights for this sample
    __shared__ float xs[ICCH][TZ+2][TY+2][TX+2];         // 4896 floats = 19584 B

    const int NTX = Dm / TX, NTY = Dm / TY, NTZ = Dm / TZ;
    int bid = blockIdx.x;
    int b   = bid / (NTX*NTY*NTZ);
    int rem = bid % (NTX*NTY*NTZ);
    int tz0 = rem / (NTY*NTX);
    int rem2= rem % (NTY*NTX);
    int ty0 = rem2 / NTX;
    int tx0 = rem2 % NTX;
    int z0 = tz0*TZ, y0 = ty0*TY, x0 = tx0*TX;

    int tid = threadIdx.x;
    int tx  = tid & 31;    // output x within tile (lane)
    int grp = tid >> 5;    // 0..7 -> pair of output channels

    // stage all weights for this sample
    const float* kwb = kw + (long)b * KWN;
    for (int i = tid; i < KWN; i += 256) wlds[i] = kwb[i];

    float acc[2][TZ][TY];
#pragma unroll
    for (int o = 0; o < 2; ++o)
#pragma unroll
        for (int i = 0; i < TZ; ++i)
#pragma unroll
            for (int j = 0; j < TY; ++j) acc[o][i][j] = 0.f;

    const float* xb = x + (long)b * ICn * Dm*Dm*Dm;

    for (int c = 0; c < ICn/ICCH; ++c) {
        __syncthreads();   // protect wlds (first iter) / xs reuse (later iters)
        // stage x chunk (with halo, zero-padded at volume edges)
        for (int i = tid; i < ICCH*(TZ+2)*(TY+2)*(TX+2); i += 256) {
            int dx = i % (TX+2);
            int r2 = i / (TX+2);
            int dy = r2 % (TY+2); r2 /= (TY+2);
            int dz = r2 % (TZ+2);
            int icl= r2 / (TZ+2);
            int gz = z0-1+dz, gy = y0-1+dy, gx = x0-1+dx;
            float v = 0.f;
            if ((unsigned)gz < (unsigned)Dm && (unsigned)gy < (unsigned)Dm &&
                (unsigned)gx < (unsigned)Dm)
                v = xb[(((long)(c*ICCH+icl)*Dm + gz)*Dm + gy)*Dm + gx];
            ((float*)xs)[i] = v;
        }
        __syncthreads();

        for (int icl = 0; icl < ICCH; ++icl) {
            int ic = c*ICCH + icl;
            // hoist this (oc-pair, ic) weight slice into registers (LDS broadcast reads)
            float w[2][27];
#pragma unroll
            for (int o = 0; o < 2; ++o)
#pragma unroll
                for (int j = 0; j < 27; ++j)
                    w[o][j] = wlds[(grp*2+o)*(ICn*KVOL) + ic*KVOL + j];

#pragma unroll
            for (int zz = 0; zz < TZ+2; ++zz) {
#pragma unroll
                for (int yy = 0; yy < TY+2; ++yy) {
                    float xv0 = xs[icl][zz][yy][tx+0];
                    float xv1 = xs[icl][zz][yy][tx+1];
                    float xv2 = xs[icl][zz][yy][tx+2];
#pragma unroll
                    for (int tzi = 0; tzi < TZ; ++tzi) {
                        int kz = zz - tzi;
                        if (kz < 0 || kz > 2) continue;
#pragma unroll
                        for (int tyi = 0; tyi < TY; ++tyi) {
                            int ky = yy - tyi;
                            if (ky < 0 || ky > 2) continue;
#pragma unroll
                            for (int o = 0; o < 2; ++o) {
                                acc[o][tzi][tyi] += xv0 * w[o][kz*9+ky*3+0]
                                                  + xv1 * w[o][kz*9+ky*3+1]
                                                  + xv2 * w[o][kz*9+ky*3+2];
                            }
                        }
                    }
                }
            }
        }
    }

    // epilogue: add bias, store
    float bi[2];
    bi[0] = bias[b*OCn + grp*2 + 0];
    bi[1] = bias[b*OCn + grp*2 + 1];
#pragma unroll
    for (int o = 0; o < 2; ++o) {
        int oc = grp*2 + o;
#pragma unroll
        for (int tzi = 0; tzi < TZ; ++tzi) {
#pragma unroll
            for (int tyi = 0; tyi < TY; ++tyi) {
                long idx = ((((long)b*OCn + oc)*Dm + (z0+tzi))*Dm + (y0+tyi))*Dm + (x0+tx);
                out[idx] = acc[o][tzi][tyi] + bi[o];
            }
        }
    }
}

extern "C" void kernel_launch(void* const* d_in, const int* in_sizes, int n_in,
                              void* d_out, int out_size, void* d_ws, size_t ws_size,
                              hipStream_t stream)
{
    const float* x   = (const float*)d_in[0];
    const float* hyp = (const float*)d_in[1];
    const float* Wk  = (const float*)d_in[2];
    const float* bk  = (const float*)d_in[3];
    const float* Wb  = (const float*)d_in[4];
    const float* bb  = (const float*)d_in[5];
    float* out  = (float*)d_out;
    float* kw   = (float*)d_ws;            // 4*6912 floats
    float* bias = kw + BSn*KWN;            // 64 floats

    hipLaunchKernelGGL(hyper_gemm_kernel, dim3((BSn*KWN + 255)/256), dim3(256), 0, stream,
                       hyp, Wk, bk, kw);
    hipLaunchKernelGGL(hyper_bias_kernel, dim3(1), dim3(64), 0, stream,
                       hyp, Wb, bb, bias);
    hipLaunchKernelGGL(conv_kernel, dim3(BSn*(Dm/TX)*(Dm/TY)*(Dm/TZ)), dim3(256), 0, stream,
                       x, kw, bias, out);
}

// Round 2
// 316.316 us; speedup vs baseline: 6.3384x; 6.3384x over previous
//
#include <hip/hip_runtime.h>

#define Dm 96
#define ICn 16
#define OCn 16
#define HYPn 128
#define BSn 4
#define NKK 14                      // 14 MFMAs of K=32: 448 = 28 taps * 16 ic (tap 27 zero-padded)
#define FRAG_ELEMS (NKK*64*8)       // 7168 bf16 per sample (A fragments in lane order)

typedef float   f32x4  __attribute__((ext_vector_type(4)));
typedef __bf16  bf16x8 __attribute__((ext_vector_type(8)));

__device__ __forceinline__ unsigned short f2bf(float f) {
    unsigned u = __builtin_bit_cast(unsigned, f);
    u = (u + 0x7FFFu + ((u >> 16) & 1u)) >> 16;
    return (unsigned short)u;
}

// ---------------- hypernetwork: A-fragments in MFMA lane order ----------------
// kwf[((b*NKK + kk)*64 + lane)*8 + j] = bf16( W[b][oc=lane&15][k=kk*32+(lane>>4)*8+j] )
// with k = tap*16 + ic (tap = kz*9+ky*3+kx), tap>=27 -> 0.
__global__ __launch_bounds__(256)
void hyper_frag_kernel(const float* __restrict__ hyp, const float* __restrict__ Wk,
                       const float* __restrict__ bk, unsigned short* __restrict__ kwf)
{
    int t = blockIdx.x * 256 + threadIdx.x;
    if (t >= BSn * FRAG_ELEMS) return;
    int j    = t & 7;
    int lane = (t >> 3) & 63;
    int rest = t >> 9;
    int kk   = rest % NKK;
    int b    = rest / NKK;
    int oc = lane & 15, hi = lane >> 4;
    int k  = kk * 32 + hi * 8 + j;
    int tap = k >> 4, ic = k & 15;
    float acc = 0.f;
    if (tap < 27) {
        int r = (oc * ICn + ic) * 27 + tap;
        const float4* w = (const float4*)(Wk + (long)r * HYPn);
        const float4* h = (const float4*)(hyp + (long)b * HYPn);
        acc = bk[r];
#pragma unroll
        for (int q = 0; q < HYPn / 4; ++q) {
            float4 a = h[q], c = w[q];
            acc += a.x * c.x + a.y * c.y + a.z * c.z + a.w * c.w;
        }
    }
    kwf[t] = f2bf(acc);
}

__global__ __launch_bounds__(64)
void hyper_bias_kernel(const float* __restrict__ hyp, const float* __restrict__ Wb,
                       const float* __restrict__ bb, float* __restrict__ bias)
{
    int t = threadIdx.x;          // 64 = 4 samples * 16 oc
    int b = t >> 4, oc = t & 15;
    const float4* w = (const float4*)(Wb + (long)oc * HYPn);
    const float4* h = (const float4*)(hyp + (long)b * HYPn);
    float acc = bb[oc];
#pragma unroll
    for (int q = 0; q < HYPn / 4; ++q) {
        float4 a = h[q], c = w[q];
        acc += a.x * c.x + a.y * c.y + a.z * c.z + a.w * c.w;
    }
    bias[t] = acc;                // [b][oc]
}

// ---------------- MFMA implicit-GEMM conv ----------------
// Block tile: 16 oc x (4z x 4y x 16x). 4 waves; wave w owns z = z0+w.
// LDS x tile: [6z][6y][18x][16ic] bf16, XOR-swizzled, zero-padded halo.
#define ZT 4
#define YT 4
#define XT 16
#define ZL 6
#define YL 6
#define XL 18
#define LDSB (ZL*YL*XL*32)          // 20736 bytes

__global__ __launch_bounds__(256, 2)
void conv_mfma_kernel(const float* __restrict__ x, const unsigned short* __restrict__ kwf,
                      const float* __restrict__ bias, float* __restrict__ out)
{
    __shared__ char smem[LDSB];

    const int NXT = Dm / XT, NYT = Dm / YT, NZT = Dm / ZT;    // 6, 24, 24
    // XCD-aware bijective swizzle (13824 % 8 == 0): each XCD gets a contiguous chunk
    int raw = blockIdx.x;
    int bid = (raw & 7) * ((BSn * NXT * NYT * NZT) / 8) + (raw >> 3);

    int txi = bid % NXT; bid /= NXT;
    int tyi = bid % NYT; bid /= NYT;
    int tzi = bid % NZT;
    int b   = bid / NZT;
    int x0 = txi * XT, y0 = tyi * YT, z0 = tzi * ZT;

    int tid = threadIdx.x;
    const float* xb = x + (long)b * ICn * Dm * Dm * Dm;

    // ---- stage x tile: fp32 -> bf16, [z][y][x][ic], swizzled ----
    for (int i = tid; i < ICn * ZL * YL * XL; i += 256) {
        int ic = i / (ZL * YL * XL);
        int r  = i % (ZL * YL * XL);
        int lz = r / (YL * XL);
        int r2 = r % (YL * XL);
        int ly = r2 / XL;
        int lx = r2 % XL;
        int gz = z0 - 1 + lz, gy = y0 - 1 + ly, gx = x0 - 1 + lx;
        float v = 0.f;
        if ((unsigned)gz < (unsigned)Dm && (unsigned)gy < (unsigned)Dm &&
            (unsigned)gx < (unsigned)Dm)
            v = xb[(((long)ic * Dm + gz) * Dm + gy) * Dm + gx];
        unsigned byte = (unsigned)((lz * YL + ly) * XL + lx) * 32u + (unsigned)ic * 2u;
        byte ^= (byte >> 3) & 16u;              // spread bank quads (see G4)
        *(unsigned short*)(smem + byte) = f2bf(v);
    }

    // ---- load A fragments (this sample's weights), reused for all 16 column-tiles ----
    int lane = tid & 63;
    int wv   = tid >> 6;                         // wave -> z offset
    const unsigned short* kwb = kwf + (long)b * FRAG_ELEMS;
    bf16x8 afr[NKK];
#pragma unroll
    for (int kk = 0; kk < NKK; ++kk)
        afr[kk] = *(const bf16x8*)(kwb + (kk * 64 + lane) * 8);

    __syncthreads();

    int n    = lane & 15;                        // spatial column (x offset)
    int hi   = lane >> 4;
    int ich  = hi & 1;                           // ic half
    int tsel = hi >> 1;                          // which tap of the pair

    float4 bv = *(const float4*)(bias + b * OCn + hi * 4);

#pragma unroll 1
    for (int ct = 0; ct < YT; ++ct) {
        unsigned sbase = (unsigned)((wv * YL + ct) * XL + n) * 32u + (unsigned)ich * 16u;
        f32x4 acc = {0.f, 0.f, 0.f, 0.f};
#pragma unroll
        for (int kk = 0; kk < NKK; ++kk) {
            int t0 = 2 * kk;
            int t1 = (2 * kk + 1 < 27) ? 2 * kk + 1 : 0;     // pad tap -> safe addr (A=0)
            const int o0 = (((t0 / 9) * YL + (t0 % 9) / 3) * XL + (t0 % 3)) * 32;
            const int o1 = (((t1 / 9) * YL + (t1 % 9) / 3) * XL + (t1 % 3)) * 32;
            unsigned byte = sbase + (unsigned)(tsel ? o1 : o0);
            byte ^= (byte >> 3) & 16u;
            bf16x8 bfr = *(const bf16x8*)(smem + byte);
            acc = __builtin_amdgcn_mfma_f32_16x16x32_bf16(afr[kk], bfr, acc, 0, 0, 0);
        }
        int zo = z0 + wv, yo = y0 + ct;
        long obase = ((((long)b * OCn + hi * 4) * Dm + zo) * Dm + yo) * Dm + x0 + n;
#pragma unroll
        for (int r = 0; r < 4; ++r)
            out[obase + (long)r * Dm * Dm * Dm] = acc[r] + ((const float*)&bv)[r];
    }
}

extern "C" void kernel_launch(void* const* d_in, const int* in_sizes, int n_in,
                              void* d_out, int out_size, void* d_ws, size_t ws_size,
                              hipStream_t stream)
{
    const float* x   = (const float*)d_in[0];
    const float* hyp = (const float*)d_in[1];
    const float* Wk  = (const float*)d_in[2];
    const float* bk  = (const float*)d_in[3];
    const float* Wb  = (const float*)d_in[4];
    const float* bb  = (const float*)d_in[5];
    float* out = (float*)d_out;

    unsigned short* kwf = (unsigned short*)d_ws;                       // 57344 B
    float* bias = (float*)((char*)d_ws + (size_t)BSn * FRAG_ELEMS * 2); // 64 floats

    hipLaunchKernelGGL(hyper_frag_kernel, dim3((BSn * FRAG_ELEMS) / 256), dim3(256), 0, stream,
                       hyp, Wk, bk, kwf);
    hipLaunchKernelGGL(hyper_bias_kernel, dim3(1), dim3(64), 0, stream,
                       hyp, Wb, bb, bias);

    const int nblk = BSn * (Dm / XT) * (Dm / YT) * (Dm / ZT);          // 13824
    hipLaunchKernelGGL(conv_mfma_kernel, dim3(nblk), dim3(256), 0, stream,
                       x, kwf, bias, out);
}

// Round 3
// 185.691 us; speedup vs baseline: 10.7972x; 1.7035x over previous
//
#include <hip/hip_runtime.h>

#define Dm 96
#define PL (Dm*Dm*Dm)               // 884736 elements per (b, ic) plane
#define ICn 16
#define OCn 16
#define HYPn 128
#define BSn 4
#define NKK 14                      // 14 MFMAs of K=32: 448 = 28 taps * 16 ic (tap 27 zero-padded)
#define FRAG_ELEMS (NKK*64*8)       // 7168 bf16 per sample (A fragments in lane order)

typedef float   f32x4  __attribute__((ext_vector_type(4)));
typedef __bf16  bf16x8 __attribute__((ext_vector_type(8)));

__device__ __forceinline__ unsigned short f2bf(float f) {
    unsigned u = __builtin_bit_cast(unsigned, f);
    u = (u + 0x7FFFu + ((u >> 16) & 1u)) >> 16;
    return (unsigned short)u;
}

// ---------------- hypernetwork: A-fragments in MFMA lane order ----------------
// kwf[((b*NKK + kk)*64 + lane)*8 + j] = bf16( W[b][oc=lane&15][k=kk*32+(lane>>4)*8+j] )
// with k = tap*16 + ic (tap = kz*9+ky*3+kx), tap>=27 -> 0.
__global__ __launch_bounds__(256)
void hyper_frag_kernel(const float* __restrict__ hyp, const float* __restrict__ Wk,
                       const float* __restrict__ bk, unsigned short* __restrict__ kwf)
{
    int t = blockIdx.x * 256 + threadIdx.x;
    if (t >= BSn * FRAG_ELEMS) return;
    int j    = t & 7;
    int lane = (t >> 3) & 63;
    int rest = t >> 9;
    int kk   = rest % NKK;
    int b    = rest / NKK;
    int oc = lane & 15, hi = lane >> 4;
    int k  = kk * 32 + hi * 8 + j;
    int tap = k >> 4, ic = k & 15;
    float acc = 0.f;
    if (tap < 27) {
        int r = (oc * ICn + ic) * 27 + tap;
        const float4* w = (const float4*)(Wk + (long)r * HYPn);
        const float4* h = (const float4*)(hyp + (long)b * HYPn);
        acc = bk[r];
#pragma unroll
        for (int q = 0; q < HYPn / 4; ++q) {
            float4 a = h[q], c = w[q];
            acc += a.x * c.x + a.y * c.y + a.z * c.z + a.w * c.w;
        }
    }
    kwf[t] = f2bf(acc);
}

__global__ __launch_bounds__(64)
void hyper_bias_kernel(const float* __restrict__ hyp, const float* __restrict__ Wb,
                       const float* __restrict__ bb, float* __restrict__ bias)
{
    int t = threadIdx.x;          // 64 = 4 samples * 16 oc
    int b = t >> 4, oc = t & 15;
    const float4* w = (const float4*)(Wb + (long)oc * HYPn);
    const float4* h = (const float4*)(hyp + (long)b * HYPn);
    float acc = bb[oc];
#pragma unroll
    for (int q = 0; q < HYPn / 4; ++q) {
        float4 a = h[q], c = w[q];
        acc += a.x * c.x + a.y * c.y + a.z * c.z + a.w * c.w;
    }
    bias[t] = acc;                // [b][oc]
}

// ---------------- MFMA implicit-GEMM conv ----------------
// Block tile: 16 oc x (4z x 8y x 16x). 4 waves; wave w owns z = z0+w, loops y in pairs.
// LDS x tile: [6z][10y][18x] spatial points, 48B stride (32B = 16 ic bf16 + 16B pad).
// Pad-48 makes both staging writes (b128) and B-reads (b128) bank-conflict-free,
// and lets every ds_read use base_vgpr + compile-time immediate (zero VALU/read).
#define ZT 4
#define YT 8
#define XT 16
#define ZL 6
#define YL 10
#define XL 18
#define SPN (ZL*YL*XL)              // 1080 spatial points
#define SSTR 48                     // bytes per spatial point
#define LDSB (SPN*SSTR)             // 51840 bytes

__device__ constexpr int tapoff(int t) {
    return (((t / 9) * YL + (t % 9) / 3) * XL + (t % 3)) * SSTR;
}

__global__ __launch_bounds__(256, 1)
void conv_mfma_kernel(const float* __restrict__ x, const unsigned short* __restrict__ kwf,
                      const float* __restrict__ bias, float* __restrict__ out)
{
    __shared__ __align__(16) char smem[LDSB];

    const int NXT = Dm / XT, NYT = Dm / YT, NZT = Dm / ZT;    // 6, 12, 24
    // XCD-aware bijective swizzle (6912 % 8 == 0)
    int raw = blockIdx.x;
    int bid = (raw & 7) * ((BSn * NXT * NYT * NZT) / 8) + (raw >> 3);

    int txi = bid % NXT; bid /= NXT;
    int tyi = bid % NYT; bid /= NYT;
    int tzi = bid % NZT;
    int b   = bid / NZT;
    int x0 = txi * XT, y0 = tyi * YT, z0 = tzi * ZT;

    int tid  = threadIdx.x;
    int lane = tid & 63;
    int wv   = tid >> 6;                         // wave -> z offset (0..3)

    const float* xb = x + (long)b * ICn * PL;

    // ---- load A fragments (this sample's weights; L2-resident, reused 8x) ----
    const unsigned short* kwb = kwf + (long)b * FRAG_ELEMS;
    bf16x8 afr[NKK];
#pragma unroll
    for (int kk = 0; kk < NKK; ++kk)
        afr[kk] = *(const bf16x8*)(kwb + (kk * 64 + lane) * 8);

    // ---- stage x tile: one task = one (z,y,x) point x 8 ic's -> 1 ds_write_b128 ----
    for (int t = tid; t < 2 * SPN; t += 256) {
        int ich = (t >= SPN) ? 1 : 0;
        int sp  = t - ich * SPN;
        int lx = sp % XL;
        int r  = sp / XL;
        int ly = r % YL;
        int lz = r / YL;
        int gz = z0 - 1 + lz, gy = y0 - 1 + ly, gx = x0 - 1 + lx;
        bf16x8 vv;
        if ((unsigned)gz < (unsigned)Dm && (unsigned)gy < (unsigned)Dm &&
            (unsigned)gx < (unsigned)Dm) {
            const float* g = xb + (long)(ich * 8) * PL + ((long)gz * Dm + gy) * Dm + gx;
#pragma unroll
            for (int q = 0; q < 8; ++q) vv[q] = (__bf16)g[(long)q * PL];
        } else {
#pragma unroll
            for (int q = 0; q < 8; ++q) vv[q] = (__bf16)0.f;
        }
        *(bf16x8*)(smem + sp * SSTR + ich * 16) = vv;
    }

    __syncthreads();

    int n    = lane & 15;                        // spatial column (x offset)
    int hi   = lane >> 4;
    int ich  = hi & 1;                           // ic half
    int tsel = hi >> 1;                          // which tap of the pair

    // per-lane B-fragment base addresses, one per kk (tap offsets folded in)
    int addrk[NKK];
#pragma unroll
    for (int kk = 0; kk < NKK; ++kk) {
        int t0 = 2 * kk;
        int t1 = (2 * kk + 1 < 27) ? 2 * kk + 1 : 0;         // pad tap -> safe addr (A=0)
        addrk[kk] = ((wv * YL) * XL + n) * SSTR + ich * 16 +
                    (tsel ? tapoff(t1) : tapoff(t0));
    }

    float4 bv = *(const float4*)(bias + b * OCn + hi * 4);

#pragma unroll 1
    for (int cp = 0; cp < YT / 2; ++cp) {
        f32x4 acc0 = {0.f, 0.f, 0.f, 0.f};
        f32x4 acc1 = {0.f, 0.f, 0.f, 0.f};
#pragma unroll
        for (int kk = 0; kk < NKK; ++kk) {
            bf16x8 f0 = *(const bf16x8*)(smem + addrk[kk]);
            bf16x8 f1 = *(const bf16x8*)(smem + addrk[kk] + XL * SSTR);
            acc0 = __builtin_amdgcn_mfma_f32_16x16x32_bf16(afr[kk], f0, acc0, 0, 0, 0);
            acc1 = __builtin_amdgcn_mfma_f32_16x16x32_bf16(afr[kk], f1, acc1, 0, 0, 0);
        }
        int zo = z0 + wv, yo = y0 + 2 * cp;
        long obase = ((((long)b * OCn + hi * 4) * Dm + zo) * Dm + yo) * Dm + x0 + n;
#pragma unroll
        for (int r = 0; r < 4; ++r) {
            out[obase + (long)r * PL]      = acc0[r] + ((const float*)&bv)[r];
            out[obase + (long)r * PL + Dm] = acc1[r] + ((const float*)&bv)[r];
        }
#pragma unroll
        for (int kk = 0; kk < NKK; ++kk) addrk[kk] += 2 * XL * SSTR;
    }
}

extern "C" void kernel_launch(void* const* d_in, const int* in_sizes, int n_in,
                              void* d_out, int out_size, void* d_ws, size_t ws_size,
                              hipStream_t stream)
{
    const float* x   = (const float*)d_in[0];
    const float* hyp = (const float*)d_in[1];
    const float* Wk  = (const float*)d_in[2];
    const float* bk  = (const float*)d_in[3];
    const float* Wb  = (const float*)d_in[4];
    const float* bb  = (const float*)d_in[5];
    float* out = (float*)d_out;

    unsigned short* kwf = (unsigned short*)d_ws;                        // 57344 B
    float* bias = (float*)((char*)d_ws + (size_t)BSn * FRAG_ELEMS * 2); // 64 floats

    hipLaunchKernelGGL(hyper_frag_kernel, dim3((BSn * FRAG_ELEMS) / 256), dim3(256), 0, stream,
                       hyp, Wk, bk, kwf);
    hipLaunchKernelGGL(hyper_bias_kernel, dim3(1), dim3(64), 0, stream,
                       hyp, Wb, bb, bias);

    const int nblk = BSn * (Dm / XT) * (Dm / YT) * (Dm / ZT);           // 6912
    hipLaunchKernelGGL(conv_mfma_kernel, dim3(nblk), dim3(256), 0, stream,
                       x, kwf, bias, out);
}